// Round 4
// baseline (1653.580 us; speedup 1.0000x reference)
//
#include <hip/hip_runtime.h>
#include <stdint.h>

#define BATCH 8192
#define ADIM 128
#define HDIM 256
#define VDIM 64
#define NSTEP 20
#define TB 16
#define ASP 20   // attr_s stride: 16B-aligned rows for b128 staging reads

typedef float v2f __attribute__((ext_vector_type(2)));
typedef union { float4 v; v2f h2[2]; float f[4]; } F4;

// packed fp32 FMA, src0 scalar-broadcast via op_sel (both halves read LO or HI of H2).
// Each half is a full-precision IEEE fma == v_fma_f32 -> bit-exact vs scalar version.
// Non-volatile + "+v" tie: schedulable, but per-accumulator order preserved by the
// data dependency -> per-acc k-ascending summation unchanged.
#define PKFMA_LO(ACC, H2, W2) \
  asm("v_pk_fma_f32 %0, %1, %2, %0 op_sel:[0,0,0] op_sel_hi:[0,1,1]" : "+v"(ACC) : "v"(H2), "v"(W2))
#define PKFMA_HI(ACC, H2, W2) \
  asm("v_pk_fma_f32 %0, %1, %2, %0 op_sel:[1,0,0] op_sel_hi:[1,1,1]" : "+v"(ACC) : "v"(H2), "v"(W2))

// ---------------- Threefry-2x32 (exactly JAX's lowering) ----------------
__device__ __forceinline__ uint32_t rotl32(uint32_t x, uint32_t d) {
  return (x << d) | (x >> (32u - d));
}
__device__ __forceinline__ void tf4(uint32_t& x0, uint32_t& x1, int r0, int r1, int r2, int r3) {
  x0 += x1; x1 = rotl32(x1, r0); x1 ^= x0;
  x0 += x1; x1 = rotl32(x1, r1); x1 ^= x0;
  x0 += x1; x1 = rotl32(x1, r2); x1 ^= x0;
  x0 += x1; x1 = rotl32(x1, r3); x1 ^= x0;
}
__device__ __forceinline__ void threefry2x32(uint32_t k0, uint32_t k1, uint32_t x0, uint32_t x1,
                                             uint32_t& o0, uint32_t& o1) {
  uint32_t k2 = k0 ^ k1 ^ 0x1BD11BDAu;
  x0 += k0; x1 += k1;
  tf4(x0, x1, 13, 15, 26, 6);  x0 += k1; x1 += k2 + 1u;
  tf4(x0, x1, 17, 29, 16, 24); x0 += k2; x1 += k0 + 2u;
  tf4(x0, x1, 13, 15, 26, 6);  x0 += k0; x1 += k1 + 3u;
  tf4(x0, x1, 17, 29, 16, 24); x0 += k1; x1 += k2 + 4u;
  tf4(x0, x1, 13, 15, 26, 6);  x0 += k2; x1 += k0 + 5u;
  o0 = x0; o1 = x1;
}

__device__ __forceinline__ float sigm(float x) { return 1.0f / (1.0f + expf(-x)); }

// ---------------- prep: repack weights ----------------
// ws layout (floats):
//   WhhG [64][256][4][4] @0       (kgroup, unit, k-within-group, gate) 1 MB
//   WaT  [128][256]      @262144  (k, unit)
//   WihT4[64][256][4]    @294912  (v, unit, gate)
// W_v is used in its NATIVE [v][k] layout.
__global__ void prep_kernel(const float* __restrict__ Whh, const float* __restrict__ Wa,
                            const float* __restrict__ Wih, float* __restrict__ ws) {
  int n = blockIdx.x * blockDim.x + threadIdx.x;
  int stride = gridDim.x * blockDim.x;
  float* WhhG  = ws;
  float* WaT   = ws + 262144;
  float* WihT4 = ws + 294912;
  for (int i = n; i < 262144; i += stride) {
    int g4 = i >> 12, u = (i >> 4) & 255, j = (i >> 2) & 3, g = i & 3;
    WhhG[i] = Whh[((g << 8) + u) * 256 + (g4 << 2) + j];
  }
  for (int i = n; i < 128 * 256; i += stride) { int k = i >> 8, uu = i & 255; WaT[i] = Wa[uu * 128 + k]; }
  for (int i = n; i < 64 * 1024; i += stride) {
    int v = i >> 10, rem = i & 1023, uu = rem >> 2, g = rem & 3;
    WihT4[i] = Wih[((g << 8) + uu) * 64 + v];
  }
}

// one k-group (4 k's) of gate FMAs for one slot, packed over the gate dim:
// acc pair 0 = gates (0,1)=(i,f), pair 1 = gates (2,3)=(g,o).
// values & per-accumulator k-order identical to the scalar version -> bit-exact.
#define GQUAD(S, K0, W0, W1, W2, W3)                                   \
  do {                                                                 \
    v2f h01 = *(const v2f*)&h_s[S][K0];                                \
    v2f h23 = *(const v2f*)&h_s[S][(K0) + 2];                          \
    PKFMA_LO(ga2[S][0], h01, W0.h2[0]);                                \
    PKFMA_LO(ga2[S][1], h01, W0.h2[1]);                                \
    PKFMA_HI(ga2[S][0], h01, W1.h2[0]);                                \
    PKFMA_HI(ga2[S][1], h01, W1.h2[1]);                                \
    PKFMA_LO(ga2[S][0], h23, W2.h2[0]);                                \
    PKFMA_LO(ga2[S][1], h23, W2.h2[1]);                                \
    PKFMA_HI(ga2[S][0], h23, W3.h2[0]);                                \
    PKFMA_HI(ga2[S][1], h23, W3.h2[1]);                                \
  } while (0)

#define GHALF(K0, W0, W1, W2, W3)                                      \
  do {                                                                 \
    GQUAD(0, K0, W0, W1, W2, W3);  GQUAD(1, K0, W0, W1, W2, W3);       \
    GQUAD(2, K0, W0, W1, W2, W3);  GQUAD(3, K0, W0, W1, W2, W3);       \
    GQUAD(4, K0, W0, W1, W2, W3);  GQUAD(5, K0, W0, W1, W2, W3);       \
    GQUAD(6, K0, W0, W1, W2, W3);  GQUAD(7, K0, W0, W1, W2, W3);       \
    GQUAD(8, K0, W0, W1, W2, W3);  GQUAD(9, K0, W0, W1, W2, W3);       \
    GQUAD(10, K0, W0, W1, W2, W3); GQUAD(11, K0, W0, W1, W2, W3);      \
    GQUAD(12, K0, W0, W1, W2, W3); GQUAD(13, K0, W0, W1, W2, W3);      \
    GQUAD(14, K0, W0, W1, W2, W3); GQUAD(15, K0, W0, W1, W2, W3);      \
  } while (0)

// ---------------- main persistent kernel ----------------
// 512 blocks x 256 threads; block owns TB=16 samples for all 21 steps.
// Lane = unit (u = 64w+lane); thread computes 4 gates x 16 samples for its unit.
// h_s[sample][k]: wave-uniform LDS broadcast reads feed v_pk_fma_f32 (2 IEEE
// FMAs/instr, packed over the GATE dim with op_sel h-broadcast) -> gate FMA
// issue slots halved: 16384 -> 8192 per wave per step.
// Cell state in LDS; Whh double-buffered (A/B) with #pragma unroll 1.
// All FMA values and per-accumulator k-order identical to R1/R3 -> bit-exact.
__global__ __launch_bounds__(256, 2) void sender_main(
    const float* __restrict__ attr, const float* __restrict__ b_a,
    const float* __restrict__ b_ih, const float* __restrict__ b_hh,
    const float* __restrict__ b_v,
    const float* __restrict__ WhhG, const float* __restrict__ Wv2,
    const float* __restrict__ WaT, const float* __restrict__ WihT4,
    float* __restrict__ out) {
  __shared__ __align__(16) float h_s[TB][HDIM];   // h_s[sample][k]
  __shared__ float c_s[TB][HDIM];                 // cell state [sample][unit]
  __shared__ __align__(16) float attr_s[ADIM][ASP];
  __shared__ float slp_s[TB], plp_s[TB], ep_s[TB];
  __shared__ int ch_s[TB];

  const int tid = threadIdx.x;
  const int w = tid >> 6;         // wave id
  const int lane = tid & 63;
  const int u = (w << 6) + lane;  // unit owned by this thread
  const int uu4 = u << 2;
  const int w4 = w << 2;          // first sample this wave samples
  const int b0 = blockIdx.x * TB;

  const float* wb  = WhhG + (u << 4);     // + (g4<<12): 64B chunk per (group,unit)
  const float* wvr = Wv2 + (lane << 8);   // W_v row for v = lane

  if (tid < TB) { slp_s[tid] = 0.0f; plp_s[tid] = 0.0f; ep_s[tid] = 1.0f; }

  // ---- stage attr tile, transposed to k-major ----
  {
    int r = tid >> 5;            // 0..7
    int cm = (tid & 31) << 2;    // 0,4,...,124
    #pragma unroll
    for (int pass = 0; pass < 2; ++pass) {
      int row = r + (pass << 3);
      F4 vv; vv.v = *(const float4*)&attr[(size_t)(b0 + row) * ADIM + cm];
      attr_s[cm + 0][row] = vv.f[0];
      attr_s[cm + 1][row] = vv.f[1];
      attr_s[cm + 2][row] = vv.f[2];
      attr_s[cm + 3][row] = vv.f[3];
    }
  }
  __syncthreads();

  // ---- h0 = attr @ W_a^T + b_a ----
  {
    float acc[16];
    #pragma unroll
    for (int s = 0; s < 16; ++s) acc[s] = 0.0f;
    #pragma unroll 2
    for (int k = 0; k < ADIM; ++k) {
      F4 a0, a1, a2, a3;
      a0.v = *(const float4*)&attr_s[k][0];
      a1.v = *(const float4*)&attr_s[k][4];
      a2.v = *(const float4*)&attr_s[k][8];
      a3.v = *(const float4*)&attr_s[k][12];
      float wa = WaT[(k << 8) + u];
      #pragma unroll
      for (int j = 0; j < 4; ++j) {
        acc[j]      = fmaf(a0.f[j], wa, acc[j]);
        acc[4 + j]  = fmaf(a1.f[j], wa, acc[4 + j]);
        acc[8 + j]  = fmaf(a2.f[j], wa, acc[8 + j]);
        acc[12 + j] = fmaf(a3.f[j], wa, acc[12 + j]);
      }
    }
    float ba = b_a[u];
    #pragma unroll
    for (int s = 0; s < 16; ++s) h_s[s][u] = acc[s] + ba;  // lane-consecutive: conflict-free
  }
  __syncthreads();

  float bg[4];  // b_ih + b_hh per gate for this unit
  #pragma unroll
  for (int g = 0; g < 4; ++g) bg[g] = b_ih[(g << 8) + u] + b_hh[(g << 8) + u];
  const float bv = b_v[lane];

  // ---- initial LSTM step, x = 0, c = 0 ----
  {
    v2f ga2[16][2];
    #pragma unroll
    for (int s = 0; s < 16; ++s) { ga2[s][0] = (v2f)(0.0f); ga2[s][1] = (v2f)(0.0f); }

    F4 p0, p1, p2, p3, q0, q1, q2, q3;
    p0.v = *(const float4*)(wb + 0);  p1.v = *(const float4*)(wb + 4);
    p2.v = *(const float4*)(wb + 8);  p3.v = *(const float4*)(wb + 12);
    #pragma unroll 1
    for (int g4 = 0; g4 < 64; g4 += 2) {
      const int k0 = g4 << 2;
      { const float* nb = wb + ((g4 + 1) << 12);
        q0.v = *(const float4*)(nb + 0);  q1.v = *(const float4*)(nb + 4);
        q2.v = *(const float4*)(nb + 8);  q3.v = *(const float4*)(nb + 12); }
      GHALF(k0, p0, p1, p2, p3);
      { const float* nb = wb + ((g4 + 2) << 12);   // g4=62 prefetches into WaT region: in-bounds, unused
        p0.v = *(const float4*)(nb + 0);  p1.v = *(const float4*)(nb + 4);
        p2.v = *(const float4*)(nb + 8);  p3.v = *(const float4*)(nb + 12); }
      GHALF(k0 + 4, q0, q1, q2, q3);
    }
    __syncthreads();  // all reads of h_s done before overwrite
    #pragma unroll
    for (int s = 0; s < 16; ++s) {
      float gi = ga2[s][0].x + bg[0];
      float gf = ga2[s][0].y + bg[1];
      float gg = ga2[s][1].x + bg[2];
      float go = ga2[s][1].y + bg[3];
      float cn = sigm(gf) * 0.0f + sigm(gi) * tanhf(gg);  // c starts at 0 (same arithmetic as R1)
      c_s[s][u] = cn;
      h_s[s][u] = sigm(go) * tanhf(cn);
    }
    __syncthreads();
  }

  // ---- 20 sampled steps ----
  #pragma unroll 1
  for (int l = 0; l < NSTEP; ++l) {
    uint32_t kl0, kl1;
    threefry2x32(0u, 42u, 0u, (uint32_t)l, kl0, kl1);

    const bool last = (l == NSTEP - 1);
    float la[4] = {0.0f, 0.0f, 0.0f, 0.0f};
    v2f ga2[16][2];

    if (!last) {
      #pragma unroll
      for (int s = 0; s < 16; ++s) { ga2[s][0] = (v2f)(0.0f); ga2[s][1] = (v2f)(0.0f); }

      F4 p0, p1, p2, p3, q0, q1, q2, q3;
      p0.v = *(const float4*)(wb + 0);  p1.v = *(const float4*)(wb + 4);
      p2.v = *(const float4*)(wb + 8);  p3.v = *(const float4*)(wb + 12);
      #pragma unroll 1
      for (int g4 = 0; g4 < 64; g4 += 2) {
        const int k0 = g4 << 2;
        { const float* nb = wb + ((g4 + 1) << 12);
          q0.v = *(const float4*)(nb + 0);  q1.v = *(const float4*)(nb + 4);
          q2.v = *(const float4*)(nb + 8);  q3.v = *(const float4*)(nb + 12); }
        GHALF(k0, p0, p1, p2, p3);
        { const float* nb = wb + ((g4 + 2) << 12);
          p0.v = *(const float4*)(nb + 0);  p1.v = *(const float4*)(nb + 4);
          p2.v = *(const float4*)(nb + 8);  p3.v = *(const float4*)(nb + 12); }
        GHALF(k0 + 4, q0, q1, q2, q3);
      }
    }

    // ---- logits for this wave's 4 samples (slots w4..w4+3), v = lane ----
    {
      F4 wvA, wvB;
      wvA.v = *(const float4*)(wvr + 0);
      #pragma unroll 1
      for (int g4 = 0; g4 < 64; g4 += 2) {
        const int k0 = g4 << 2;
        wvB.v = *(const float4*)(wvr + k0 + 4);
        #pragma unroll
        for (int db = 0; db < 4; ++db) {
          F4 h4; h4.v = *(const float4*)&h_s[w4 + db][k0];
          la[db] = fmaf(h4.f[0], wvA.f[0], la[db]);
          la[db] = fmaf(h4.f[1], wvA.f[1], la[db]);
          la[db] = fmaf(h4.f[2], wvA.f[2], la[db]);
          la[db] = fmaf(h4.f[3], wvA.f[3], la[db]);
        }
        if (g4 + 2 < 64) wvA.v = *(const float4*)(wvr + k0 + 8);  // guard: no OOB past W_v
        #pragma unroll
        for (int db = 0; db < 4; ++db) {
          F4 h4; h4.v = *(const float4*)&h_s[w4 + db][k0 + 4];
          la[db] = fmaf(h4.f[0], wvB.f[0], la[db]);
          la[db] = fmaf(h4.f[1], wvB.f[1], la[db]);
          la[db] = fmaf(h4.f[2], wvB.f[2], la[db]);
          la[db] = fmaf(h4.f[3], wvB.f[3], la[db]);
        }
      }
    }

    // ---- sampling: wave w handles samples w4..w4+3; lane holds logit[b][lane] ----
    #pragma unroll
    for (int db = 0; db < 4; ++db) {
      float x = la[db] + bv;  // logits = h@W_v^T + b_v
      float m = x;
      #pragma unroll
      for (int o = 32; o > 0; o >>= 1) m = fmaxf(m, __shfl_xor(m, o));
      float e = expf(x - m);
      float s = e;
      #pragma unroll
      for (int o = 32; o > 0; o >>= 1) s += __shfl_xor(s, o);
      float lse = logf(s);
      float logp = x - m - lse;
      float p = expf(logp);
      float pe = p * logp;
      #pragma unroll
      for (int o = 32; o > 0; o >>= 1) pe += __shfl_xor(pe, o);
      uint32_t idx = ((uint32_t)(b0 + w4 + db) << 6) | (uint32_t)lane;
      uint32_t r0, r1;
      threefry2x32(kl0, kl1, 0u, idx, r0, r1);
      uint32_t bits = r0 ^ r1;
      float f01 = __uint_as_float((bits >> 9) | 0x3f800000u) - 1.0f;
      const float TINY = 1.17549435e-38f;
      float uu2 = fmaxf(TINY, f01 + TINY);
      float gn = -logf(-logf(uu2));
      float y = gn + x;
      float by = y; int bi = lane;
      #pragma unroll
      for (int o = 32; o > 0; o >>= 1) {
        float oy = __shfl_xor(by, o);
        int oi = __shfl_xor(bi, o);
        if (oy > by || (oy == by && oi < bi)) { by = oy; bi = oi; }
      }
      float lp = __shfl(logp, bi, 64);
      if (lane == 0) {
        int bb = w4 + db;
        ch_s[bb] = bi;
        slp_s[bb] += lp;
        plp_s[bb] += pe;
        ep_s[bb] *= expf(lp);
        out[(size_t)(b0 + bb) * NSTEP + l] = (float)bi;
      }
    }

    if (!last) {
      __syncthreads();  // everyone finished reading h_s; ch_s visible
      #pragma unroll
      for (int s = 0; s < 16; ++s) {
        F4 wi; wi.v = *(const float4*)&WihT4[(ch_s[s] << 10) + uu4];
        float cr = c_s[s][u];
        float gi = ga2[s][0].x + wi.f[0] + bg[0];
        float gf = ga2[s][0].y + wi.f[1] + bg[1];
        float gg = ga2[s][1].x + wi.f[2] + bg[2];
        float go = ga2[s][1].y + wi.f[3] + bg[3];
        float cn = sigm(gf) * cr + sigm(gi) * tanhf(gg);
        c_s[s][u] = cn;
        h_s[s][u] = sigm(go) * tanhf(cn);
      }
      __syncthreads();
    }
  }

  __syncthreads();
  if (tid < TB) {
    int bb = b0 + tid;
    out[(size_t)BATCH * NSTEP + bb]             = slp_s[tid];
    out[(size_t)BATCH * NSTEP + BATCH + bb]     = plp_s[tid];
    out[(size_t)BATCH * NSTEP + 2 * BATCH + bb] = ep_s[tid];
  }
}

extern "C" void kernel_launch(void* const* d_in, const int* in_sizes, int n_in,
                              void* d_out, int out_size, void* d_ws, size_t ws_size,
                              hipStream_t stream) {
  // setup_inputs order:
  // 0 attrVector [8192,128], 1 W_a [256,128], 2 b_a [256], 3 W_ih [1024,64],
  // 4 W_hh [1024,256], 5 b_ih [1024], 6 b_hh [1024], 7 W_v [64,256], 8 b_v [64]
  const float* attr = (const float*)d_in[0];
  const float* W_a  = (const float*)d_in[1];
  const float* b_a  = (const float*)d_in[2];
  const float* W_ih = (const float*)d_in[3];
  const float* W_hh = (const float*)d_in[4];
  const float* b_ih = (const float*)d_in[5];
  const float* b_hh = (const float*)d_in[6];
  const float* W_v  = (const float*)d_in[7];
  const float* b_v  = (const float*)d_in[8];
  float* ws = (float*)d_ws;

  prep_kernel<<<256, 256, 0, stream>>>(W_hh, W_a, W_ih, ws);
  sender_main<<<BATCH / TB, 256, 0, stream>>>(
      attr, b_a, b_ih, b_hh, b_v,
      ws, W_v, ws + 262144, ws + 294912,
      (float*)d_out);
}

// Round 5
// 1618.213 us; speedup vs baseline: 1.0219x; 1.0219x over previous
//
#include <hip/hip_runtime.h>
#include <stdint.h>

#define BATCH 8192
#define ADIM 128
#define HDIM 256
#define VDIM 64
#define NSTEP 20
#define TB 16
#define HSP 17   // h_s/c_s stride: odd -> lane-distributed b32 reads conflict-free
#define ASP 20   // attr_s stride: 16B-aligned rows for b128 staging reads

typedef float v2f __attribute__((ext_vector_type(2)));
typedef union { float4 v; v2f h2[2]; float f[4]; } F4;

// ---------------- Threefry-2x32 (exactly JAX's lowering) ----------------
__device__ __forceinline__ uint32_t rotl32(uint32_t x, uint32_t d) {
  return (x << d) | (x >> (32u - d));
}
__device__ __forceinline__ void tf4(uint32_t& x0, uint32_t& x1, int r0, int r1, int r2, int r3) {
  x0 += x1; x1 = rotl32(x1, r0); x1 ^= x0;
  x0 += x1; x1 = rotl32(x1, r1); x1 ^= x0;
  x0 += x1; x1 = rotl32(x1, r2); x1 ^= x0;
  x0 += x1; x1 = rotl32(x1, r3); x1 ^= x0;
}
__device__ __forceinline__ void threefry2x32(uint32_t k0, uint32_t k1, uint32_t x0, uint32_t x1,
                                             uint32_t& o0, uint32_t& o1) {
  uint32_t k2 = k0 ^ k1 ^ 0x1BD11BDAu;
  x0 += k0; x1 += k1;
  tf4(x0, x1, 13, 15, 26, 6);  x0 += k1; x1 += k2 + 1u;
  tf4(x0, x1, 17, 29, 16, 24); x0 += k2; x1 += k0 + 2u;
  tf4(x0, x1, 13, 15, 26, 6);  x0 += k0; x1 += k1 + 3u;
  tf4(x0, x1, 17, 29, 16, 24); x0 += k1; x1 += k2 + 4u;
  tf4(x0, x1, 13, 15, 26, 6);  x0 += k2; x1 += k0 + 5u;
  o0 = x0; o1 = x1;
}

__device__ __forceinline__ float sigm(float x) { return 1.0f / (1.0f + expf(-x)); }

// wave-uniform broadcast of lane t's value (compiler-handled hazards)
__device__ __forceinline__ float bcast(float x, int t) {
  return __int_as_float(__builtin_amdgcn_readlane(__float_as_int(x), t));
}

// ---------------- prep: repack weights (R1 layout) ----------------
// ws layout (floats): WhhT4[256][256][4] @0      (k, unit, gate)  1 MB
//                     WvT  [256][64]     @262144 (k, v)
//                     WaT  [128][256]    @278528 (k, unit)
//                     WihT4[64][256][4]  @311296 (v, unit, gate)
__global__ void prep_kernel(const float* __restrict__ Whh, const float* __restrict__ Wv,
                            const float* __restrict__ Wa, const float* __restrict__ Wih,
                            float* __restrict__ ws) {
  int n = blockIdx.x * blockDim.x + threadIdx.x;
  int stride = gridDim.x * blockDim.x;
  float* WhhT4 = ws;
  float* WvT   = ws + 262144;
  float* WaT   = ws + 278528;
  float* WihT4 = ws + 311296;
  for (int i = n; i < 256 * 1024; i += stride) {
    int k = i >> 10, rem = i & 1023, u = rem >> 2, g = rem & 3;
    WhhT4[i] = Whh[((g << 8) + u) * 256 + k];
  }
  for (int i = n; i < 256 * 64; i += stride) { int k = i >> 6, v = i & 63; WvT[i] = Wv[v * 256 + k]; }
  for (int i = n; i < 128 * 256; i += stride) { int k = i >> 8, uu = i & 255; WaT[i] = Wa[uu * 128 + k]; }
  for (int i = n; i < 64 * 1024; i += stride) {
    int v = i >> 10, rem = i & 1023, uu = rem >> 2, g = rem & 3;
    WihT4[i] = Wih[((g << 8) + uu) * 64 + v];
  }
}

// ---- slot-pair gate block: k = k0+T0, k0+T1 for slots SA, SB ----
// v_readlane (R1's broadcast, VALU pipe) fills pinned pair s[90:91] with
// h(T0),h(T1) for slot SA and s[92:93] for slot SB; v_pk_fma_f32 consumes the
// pair via op_sel lo/lo (k=T0) and hi/hi (k=T1) -- op_sel routing HW-validated
// in R4. Each pk half is IEEE fma; per-acc k order T0 then T1 (ascending) ->
// bit-exact vs R1's scalar version. SGPR write->read gap >= 3 instrs.
#define SPBLK(SA, SB, T0, T1)                                                              \
  asm("v_readlane_b32 s90, %[ha], " #T0 "\n\t"                                             \
      "v_readlane_b32 s91, %[ha], " #T1 "\n\t"                                             \
      "v_readlane_b32 s92, %[hb], " #T0 "\n\t"                                             \
      "v_readlane_b32 s93, %[hb], " #T1 "\n\t"                                             \
      "v_pk_fma_f32 %[aA0], s[90:91], %[w0A], %[aA0] op_sel:[0,0,0] op_sel_hi:[0,1,1]\n\t" \
      "v_pk_fma_f32 %[aA1], s[90:91], %[w1A], %[aA1] op_sel:[0,0,0] op_sel_hi:[0,1,1]\n\t" \
      "v_pk_fma_f32 %[aA0], s[90:91], %[w0B], %[aA0] op_sel:[1,0,0] op_sel_hi:[1,1,1]\n\t" \
      "v_pk_fma_f32 %[aA1], s[90:91], %[w1B], %[aA1] op_sel:[1,0,0] op_sel_hi:[1,1,1]\n\t" \
      "v_pk_fma_f32 %[aB0], s[92:93], %[w0A], %[aB0] op_sel:[0,0,0] op_sel_hi:[0,1,1]\n\t" \
      "v_pk_fma_f32 %[aB1], s[92:93], %[w1A], %[aB1] op_sel:[0,0,0] op_sel_hi:[0,1,1]\n\t" \
      "v_pk_fma_f32 %[aB0], s[92:93], %[w0B], %[aB0] op_sel:[1,0,0] op_sel_hi:[1,1,1]\n\t" \
      "v_pk_fma_f32 %[aB1], s[92:93], %[w1B], %[aB1] op_sel:[1,0,0] op_sel_hi:[1,1,1]"     \
      : [aA0]"+v"(ga01[SA]), [aA1]"+v"(ga23[SA]),                                          \
        [aB0]"+v"(ga01[SB]), [aB1]"+v"(ga23[SB])                                           \
      : [ha]"v"(hch[SA]), [hb]"v"(hch[SB]),                                                \
        [w0A]"v"(wkA.h2[0]), [w1A]"v"(wkA.h2[1]),                                          \
        [w0B]"v"(wkB.h2[0]), [w1B]"v"(wkB.h2[1])                                           \
      : "s90","s91","s92","s93")

// same + logit FMAs (slots SA,SB in 0..3; la index = slot; k-ascending like R1)
#define SPBLK_L(SA, SB, T0, T1)                                                            \
  asm("v_readlane_b32 s90, %[ha], " #T0 "\n\t"                                             \
      "v_readlane_b32 s91, %[ha], " #T1 "\n\t"                                             \
      "v_readlane_b32 s92, %[hb], " #T0 "\n\t"                                             \
      "v_readlane_b32 s93, %[hb], " #T1 "\n\t"                                             \
      "v_pk_fma_f32 %[aA0], s[90:91], %[w0A], %[aA0] op_sel:[0,0,0] op_sel_hi:[0,1,1]\n\t" \
      "v_pk_fma_f32 %[aA1], s[90:91], %[w1A], %[aA1] op_sel:[0,0,0] op_sel_hi:[0,1,1]\n\t" \
      "v_pk_fma_f32 %[aA0], s[90:91], %[w0B], %[aA0] op_sel:[1,0,0] op_sel_hi:[1,1,1]\n\t" \
      "v_pk_fma_f32 %[aA1], s[90:91], %[w1B], %[aA1] op_sel:[1,0,0] op_sel_hi:[1,1,1]\n\t" \
      "v_fma_f32 %[lA], s90, %[wv0], %[lA]\n\t"                                            \
      "v_fma_f32 %[lA], s91, %[wv1], %[lA]\n\t"                                            \
      "v_pk_fma_f32 %[aB0], s[92:93], %[w0A], %[aB0] op_sel:[0,0,0] op_sel_hi:[0,1,1]\n\t" \
      "v_pk_fma_f32 %[aB1], s[92:93], %[w1A], %[aB1] op_sel:[0,0,0] op_sel_hi:[0,1,1]\n\t" \
      "v_pk_fma_f32 %[aB0], s[92:93], %[w0B], %[aB0] op_sel:[1,0,0] op_sel_hi:[1,1,1]\n\t" \
      "v_pk_fma_f32 %[aB1], s[92:93], %[w1B], %[aB1] op_sel:[1,0,0] op_sel_hi:[1,1,1]\n\t" \
      "v_fma_f32 %[lB], s92, %[wv0], %[lB]\n\t"                                            \
      "v_fma_f32 %[lB], s93, %[wv1], %[lB]"                                                \
      : [aA0]"+v"(ga01[SA]), [aA1]"+v"(ga23[SA]),                                          \
        [aB0]"+v"(ga01[SB]), [aB1]"+v"(ga23[SB]),                                          \
        [lA]"+v"(la[SA]), [lB]"+v"(la[SB])                                                 \
      : [ha]"v"(hch[SA]), [hb]"v"(hch[SB]),                                                \
        [w0A]"v"(wkA.h2[0]), [w1A]"v"(wkA.h2[1]),                                          \
        [w0B]"v"(wkB.h2[0]), [w1B]"v"(wkB.h2[1]),                                          \
        [wv0]"v"(wv0), [wv1]"v"(wv1)                                                       \
      : "s90","s91","s92","s93")

#define TPAIR(T0, T1)                                                  \
  do {                                                                 \
    F4 wkA, wkB;                                                       \
    wkA.v = *(const float4*)&WhhT4[((k0 + T0) << 10) + uu4];           \
    wkB.v = *(const float4*)&WhhT4[((k0 + T1) << 10) + uu4];           \
    float wv0 = WvT[((k0 + T0) << 6) | lane];                          \
    float wv1 = WvT[((k0 + T1) << 6) | lane];                          \
    SPBLK_L(0, 1, T0, T1);                                             \
    SPBLK_L(2, 3, T0, T1);                                             \
    SPBLK(4, 5, T0, T1);   SPBLK(6, 7, T0, T1);                        \
    SPBLK(8, 9, T0, T1);   SPBLK(10, 11, T0, T1);                      \
    SPBLK(12, 13, T0, T1); SPBLK(14, 15, T0, T1);                      \
  } while (0)

// ---------------- main persistent kernel ----------------
// 512 blocks x 256 threads; block owns TB=16 samples for all 21 steps.
// Lane = unit (u = 64w+lane); thread computes 4 gates x 16 samples for its unit.
// h broadcast: R1's lane-distributed ds_read_b32 (conflict-free, 1KB useful/read)
// + v_readlane -> SGPR pair -> v_pk_fma_f32 (2 IEEE FMAs/instr, gate-packed).
// Avoids R3/R4's wave-uniform-LDS-read bottleneck (16 useful B per 12cy LDS slot)
// AND halves R1's FMA issue count. Per-wave slot rotation (slot s = phys
// (s+4w)&15) keeps logit samples at slots 0..3. Cell state in LDS (c_s).
// All FMA values and per-accumulator k-order identical to R1 -> bit-exact.
__global__ __launch_bounds__(256, 2) void sender_main(
    const float* __restrict__ attr, const float* __restrict__ b_a,
    const float* __restrict__ b_ih, const float* __restrict__ b_hh,
    const float* __restrict__ b_v,
    const float* __restrict__ WhhT4, const float* __restrict__ WvT,
    const float* __restrict__ WaT, const float* __restrict__ WihT4,
    float* __restrict__ out) {
  __shared__ float h_s[HDIM][HSP];                    // h_s[k][phys sample]
  __shared__ float c_s[HDIM][HSP];                    // c_s[unit][phys sample]
  __shared__ __align__(16) float attr_s[ADIM][ASP];   // attr_s[k][sample]
  __shared__ float slp_s[TB], plp_s[TB], ep_s[TB];
  __shared__ int ch_s[TB];

  const int tid = threadIdx.x;
  const int w = tid >> 6;         // wave id
  const int lane = tid & 63;
  const int u = (w << 6) + lane;  // unit owned by this thread
  const int uu4 = u << 2;
  const int w4 = w << 2;          // first (physical) sample this wave samples
  const int b0 = blockIdx.x * TB;

  if (tid < TB) { slp_s[tid] = 0.0f; plp_s[tid] = 0.0f; ep_s[tid] = 1.0f; }

  // ---- stage attr tile, transposed to k-major ----
  {
    int r = tid >> 5;            // 0..7
    int cm = (tid & 31) << 2;    // 0,4,...,124
    #pragma unroll
    for (int pass = 0; pass < 2; ++pass) {
      int row = r + (pass << 3);
      F4 vv; vv.v = *(const float4*)&attr[(size_t)(b0 + row) * ADIM + cm];
      attr_s[cm + 0][row] = vv.f[0];
      attr_s[cm + 1][row] = vv.f[1];
      attr_s[cm + 2][row] = vv.f[2];
      attr_s[cm + 3][row] = vv.f[3];
    }
  }
  __syncthreads();

  // ---- h0 = attr @ W_a^T + b_a : acc[phys sample] for this thread's unit ----
  {
    float acc[16];
    #pragma unroll
    for (int s = 0; s < 16; ++s) acc[s] = 0.0f;
    #pragma unroll 2
    for (int k = 0; k < ADIM; ++k) {
      F4 a0, a1, a2, a3;
      a0.v = *(const float4*)&attr_s[k][0];
      a1.v = *(const float4*)&attr_s[k][4];
      a2.v = *(const float4*)&attr_s[k][8];
      a3.v = *(const float4*)&attr_s[k][12];
      float wa = WaT[(k << 8) + u];
      #pragma unroll
      for (int j = 0; j < 4; ++j) {
        acc[j]      = fmaf(a0.f[j], wa, acc[j]);
        acc[4 + j]  = fmaf(a1.f[j], wa, acc[4 + j]);
        acc[8 + j]  = fmaf(a2.f[j], wa, acc[8 + j]);
        acc[12 + j] = fmaf(a3.f[j], wa, acc[12 + j]);
      }
    }
    float ba = b_a[u];
    #pragma unroll
    for (int s = 0; s < 16; ++s) h_s[u][s] = acc[s] + ba;
  }
  __syncthreads();

  float bg[4];  // b_ih + b_hh per gate for this unit
  #pragma unroll
  for (int g = 0; g < 4; ++g) bg[g] = b_ih[(g << 8) + u] + b_hh[(g << 8) + u];
  const float bv = b_v[lane];

  // ---- initial LSTM step, x = 0, c = 0 (R1's scalar path, c -> LDS) ----
  {
    float ga[16][4];
    #pragma unroll
    for (int s = 0; s < 16; ++s)
      #pragma unroll
      for (int g = 0; g < 4; ++g) ga[s][g] = 0.0f;
    #pragma unroll 1
    for (int kc = 0; kc < 16; ++kc) {
      const int k0 = kc << 4;
      const int kk = k0 + (lane & 15);
      float hch[16];
      #pragma unroll
      for (int s = 0; s < 16; ++s) hch[s] = h_s[kk][(s + w4) & 15];
      #pragma unroll
      for (int t = 0; t < 16; ++t) {
        const int k = k0 + t;
        F4 wv4; wv4.v = *(const float4*)&WhhT4[(k << 10) + uu4];
        #pragma unroll
        for (int s = 0; s < 16; ++s) {
          float hb = bcast(hch[s], t);
          ga[s][0] = fmaf(hb, wv4.f[0], ga[s][0]);
          ga[s][1] = fmaf(hb, wv4.f[1], ga[s][1]);
          ga[s][2] = fmaf(hb, wv4.f[2], ga[s][2]);
          ga[s][3] = fmaf(hb, wv4.f[3], ga[s][3]);
        }
      }
    }
    __syncthreads();  // all reads of h_s done before overwrite
    #pragma unroll
    for (int s = 0; s < 16; ++s) {
      const int sp = (s + w4) & 15;
      float gi = ga[s][0] + bg[0];
      float gf = ga[s][1] + bg[1];
      float gg = ga[s][2] + bg[2];
      float go = ga[s][3] + bg[3];
      float cn = sigm(gf) * 0.0f + sigm(gi) * tanhf(gg);
      c_s[u][sp] = cn;
      h_s[u][sp] = sigm(go) * tanhf(cn);
    }
    __syncthreads();
  }

  // ---- 20 sampled steps ----
  #pragma unroll 1
  for (int l = 0; l < NSTEP; ++l) {
    uint32_t kl0, kl1;
    threefry2x32(0u, 42u, 0u, (uint32_t)l, kl0, kl1);

    const bool last = (l == NSTEP - 1);
    float la[4] = {0.0f, 0.0f, 0.0f, 0.0f};  // logits for phys samples w4..w4+3, v=lane
    v2f ga01[16], ga23[16];                  // [slot]: gates (i,f) and (g,o)

    if (!last) {
      #pragma unroll
      for (int s = 0; s < 16; ++s) { ga01[s] = (v2f)(0.0f); ga23[s] = (v2f)(0.0f); }
      #pragma unroll 1
      for (int kc = 0; kc < 16; ++kc) {
        const int k0 = kc << 4;
        const int kk = k0 + (lane & 15);
        float hch[16];
        #pragma unroll
        for (int s = 0; s < 16; ++s) hch[s] = h_s[kk][(s + w4) & 15];
        TPAIR(0, 1);   TPAIR(2, 3);   TPAIR(4, 5);   TPAIR(6, 7);
        TPAIR(8, 9);   TPAIR(10, 11); TPAIR(12, 13); TPAIR(14, 15);
      }
    } else {
      // logits only (R1's scalar path)
      #pragma unroll 1
      for (int kc = 0; kc < 16; ++kc) {
        const int k0 = kc << 4;
        const int kk = k0 + (lane & 15);
        float hch[4];
        #pragma unroll
        for (int s = 0; s < 4; ++s) hch[s] = h_s[kk][(s + w4) & 15];
        #pragma unroll
        for (int t = 0; t < 16; ++t) {
          const int k = k0 + t;
          float wvv = WvT[(k << 6) | lane];
          #pragma unroll
          for (int s = 0; s < 4; ++s) la[s] = fmaf(bcast(hch[s], t), wvv, la[s]);
        }
      }
    }

    // ---- sampling: wave w handles phys samples w4..w4+3; lane holds logit[b][lane] ----
    #pragma unroll
    for (int db = 0; db < 4; ++db) {
      float x = la[db] + bv;  // logits = h@W_v^T + b_v
      float m = x;
      #pragma unroll
      for (int o = 32; o > 0; o >>= 1) m = fmaxf(m, __shfl_xor(m, o));
      float e = expf(x - m);
      float s = e;
      #pragma unroll
      for (int o = 32; o > 0; o >>= 1) s += __shfl_xor(s, o);
      float lse = logf(s);
      float logp = x - m - lse;
      float p = expf(logp);
      float pe = p * logp;
      #pragma unroll
      for (int o = 32; o > 0; o >>= 1) pe += __shfl_xor(pe, o);
      uint32_t idx = ((uint32_t)(b0 + w4 + db) << 6) | (uint32_t)lane;
      uint32_t r0, r1;
      threefry2x32(kl0, kl1, 0u, idx, r0, r1);
      uint32_t bits = r0 ^ r1;
      float f01 = __uint_as_float((bits >> 9) | 0x3f800000u) - 1.0f;
      const float TINY = 1.17549435e-38f;
      float uu2 = fmaxf(TINY, f01 + TINY);
      float gn = -logf(-logf(uu2));
      float y = gn + x;
      float by = y; int bi = lane;
      #pragma unroll
      for (int o = 32; o > 0; o >>= 1) {
        float oy = __shfl_xor(by, o);
        int oi = __shfl_xor(bi, o);
        if (oy > by || (oy == by && oi < bi)) { by = oy; bi = oi; }
      }
      float lp = __shfl(logp, bi, 64);
      if (lane == 0) {
        int bb = w4 + db;
        ch_s[bb] = bi;
        slp_s[bb] += lp;
        plp_s[bb] += pe;
        ep_s[bb] *= expf(lp);
        out[(size_t)(b0 + bb) * NSTEP + l] = (float)bi;
      }
    }

    if (!last) {
      __syncthreads();  // everyone finished reading h_s; ch_s visible
      #pragma unroll
      for (int s = 0; s < 16; ++s) {
        const int sp = (s + w4) & 15;  // physical sample for this slot
        F4 wi; wi.v = *(const float4*)&WihT4[(ch_s[sp] << 10) + uu4];
        float cr = c_s[u][sp];
        float gi = ga01[s].x + wi.f[0] + bg[0];
        float gf = ga01[s].y + wi.f[1] + bg[1];
        float gg = ga23[s].x + wi.f[2] + bg[2];
        float go = ga23[s].y + wi.f[3] + bg[3];
        float cn = sigm(gf) * cr + sigm(gi) * tanhf(gg);
        c_s[u][sp] = cn;
        h_s[u][sp] = sigm(go) * tanhf(cn);
      }
      __syncthreads();
    }
  }

  __syncthreads();
  if (tid < TB) {
    int bb = b0 + tid;
    out[(size_t)BATCH * NSTEP + bb]             = slp_s[tid];
    out[(size_t)BATCH * NSTEP + BATCH + bb]     = plp_s[tid];
    out[(size_t)BATCH * NSTEP + 2 * BATCH + bb] = ep_s[tid];
  }
}

extern "C" void kernel_launch(void* const* d_in, const int* in_sizes, int n_in,
                              void* d_out, int out_size, void* d_ws, size_t ws_size,
                              hipStream_t stream) {
  // setup_inputs order:
  // 0 attrVector [8192,128], 1 W_a [256,128], 2 b_a [256], 3 W_ih [1024,64],
  // 4 W_hh [1024,256], 5 b_ih [1024], 6 b_hh [1024], 7 W_v [64,256], 8 b_v [64]
  const float* attr = (const float*)d_in[0];
  const float* W_a  = (const float*)d_in[1];
  const float* b_a  = (const float*)d_in[2];
  const float* W_ih = (const float*)d_in[3];
  const float* W_hh = (const float*)d_in[4];
  const float* b_ih = (const float*)d_in[5];
  const float* b_hh = (const float*)d_in[6];
  const float* W_v  = (const float*)d_in[7];
  const float* b_v  = (const float*)d_in[8];
  float* ws = (float*)d_ws;

  prep_kernel<<<256, 256, 0, stream>>>(W_hh, W_v, W_a, W_ih, ws);
  sender_main<<<BATCH / TB, 256, 0, stream>>>(
      attr, b_a, b_ih, b_hh, b_v,
      ws, ws + 262144, ws + 278528, ws + 311296,
      (float*)d_out);
}

// Round 6
// 1524.459 us; speedup vs baseline: 1.0847x; 1.0615x over previous
//
#include <hip/hip_runtime.h>
#include <stdint.h>

#define BATCH 8192
#define ADIM 128
#define HDIM 256
#define VDIM 64
#define NSTEP 20
#define TB 8     // samples per block: 1024 blocks -> 4 blocks/CU -> 4 waves/SIMD
#define HSP 9    // h_s stride (floats): ODD -> lane-distributed b32 reads are conflict-free
#define ASP 12   // attr_s stride: 48B rows, 16B-aligned for b128 staging reads

typedef union { float4 v; float f[4]; } F4;

// ---------------- Threefry-2x32 (exactly JAX's lowering) ----------------
__device__ __forceinline__ uint32_t rotl32(uint32_t x, uint32_t d) {
  return (x << d) | (x >> (32u - d));
}
__device__ __forceinline__ void tf4(uint32_t& x0, uint32_t& x1, int r0, int r1, int r2, int r3) {
  x0 += x1; x1 = rotl32(x1, r0); x1 ^= x0;
  x0 += x1; x1 = rotl32(x1, r1); x1 ^= x0;
  x0 += x1; x1 = rotl32(x1, r2); x1 ^= x0;
  x0 += x1; x1 = rotl32(x1, r3); x1 ^= x0;
}
__device__ __forceinline__ void threefry2x32(uint32_t k0, uint32_t k1, uint32_t x0, uint32_t x1,
                                             uint32_t& o0, uint32_t& o1) {
  uint32_t k2 = k0 ^ k1 ^ 0x1BD11BDAu;
  x0 += k0; x1 += k1;
  tf4(x0, x1, 13, 15, 26, 6);  x0 += k1; x1 += k2 + 1u;
  tf4(x0, x1, 17, 29, 16, 24); x0 += k2; x1 += k0 + 2u;
  tf4(x0, x1, 13, 15, 26, 6);  x0 += k0; x1 += k1 + 3u;
  tf4(x0, x1, 17, 29, 16, 24); x0 += k1; x1 += k2 + 4u;
  tf4(x0, x1, 13, 15, 26, 6);  x0 += k2; x1 += k0 + 5u;
  o0 = x0; o1 = x1;
}

__device__ __forceinline__ float sigm(float x) { return 1.0f / (1.0f + expf(-x)); }

// wave-uniform broadcast of lane t's value -> SGPR (feeds v_fma scalar slot)
__device__ __forceinline__ float bcast(float x, int t) {
  return __int_as_float(__builtin_amdgcn_readlane(__float_as_int(x), t));
}

// ---------------- prep: repack weights, gate-interleaved per unit ----------------
// ws layout (floats): WhhT4[256][256][4] @0      (k, unit, gate)  1 MB
//                     WvT  [256][64]     @262144 (k, v)
//                     WaT  [128][256]    @278528 (k, unit)
//                     WihT4[64][256][4]  @311296 (v, unit, gate)
__global__ void prep_kernel(const float* __restrict__ Whh, const float* __restrict__ Wv,
                            const float* __restrict__ Wa, const float* __restrict__ Wih,
                            float* __restrict__ ws) {
  int n = blockIdx.x * blockDim.x + threadIdx.x;
  int stride = gridDim.x * blockDim.x;
  float* WhhT4 = ws;
  float* WvT   = ws + 262144;
  float* WaT   = ws + 278528;
  float* WihT4 = ws + 311296;
  for (int i = n; i < 256 * 1024; i += stride) {
    int k = i >> 10, rem = i & 1023, u = rem >> 2, g = rem & 3;
    WhhT4[i] = Whh[((g << 8) + u) * 256 + k];
  }
  for (int i = n; i < 256 * 64; i += stride) { int k = i >> 6, v = i & 63; WvT[i] = Wv[v * 256 + k]; }
  for (int i = n; i < 128 * 256; i += stride) { int k = i >> 8, uu = i & 255; WaT[i] = Wa[uu * 128 + k]; }
  for (int i = n; i < 64 * 1024; i += stride) {
    int v = i >> 10, rem = i & 1023, uu = rem >> 2, g = rem & 3;
    WihT4[i] = Wih[((g << 8) + uu) * 64 + v];
  }
}

// ---------------- main persistent kernel ----------------
// 1024 blocks x 256 threads; block owns TB=8 samples for all 21 steps.
// R6 vs R1: only the occupancy geometry changes. R2-R5 proved the kernel is
// fp32-FMA-EXECUTION-bound (pk_fma = 2x cycles, no throughput gain; LDS
// broadcast loses to the LDS return path), so the remaining lever is the
// 24% VALU idle at 2 waves/SIMD. TB=8 -> 1024 blocks = 4 blocks/CU =
// 4 waves/SIMD; VGPR drops (ga 32 regs, c_r 8) so __launch_bounds__(256,4)
// holds without spill. All per-sample arithmetic and per-accumulator
// k-ascending order identical to R1 -> bit-exact.
// Lane = unit (u = 64w+lane); thread computes 4 gates x 8 samples for its unit.
// Per-wave sample rotation: slot s holds PHYSICAL sample (s+2w)&7, so the
// wave's logit samples are always slots 0..1 (compile-time register indices).
__global__ __launch_bounds__(256, 4) void sender_main(
    const float* __restrict__ attr, const float* __restrict__ b_a,
    const float* __restrict__ b_ih, const float* __restrict__ b_hh,
    const float* __restrict__ b_v,
    const float* __restrict__ WhhT4, const float* __restrict__ WvT,
    const float* __restrict__ WaT, const float* __restrict__ WihT4,
    float* __restrict__ out) {
  __shared__ float h_s[HDIM][HSP];                    // h_s[k][phys sample]
  __shared__ __align__(16) float attr_s[ADIM][ASP];   // attr_s[k][sample]
  __shared__ float slp_s[TB], plp_s[TB], ep_s[TB];
  __shared__ int ch_s[TB];

  const int tid = threadIdx.x;
  const int w = tid >> 6;         // wave id
  const int lane = tid & 63;
  const int u = (w << 6) + lane;  // unit owned by this thread
  const int w2 = w << 1;          // first (physical) sample this wave samples
  const int b0 = blockIdx.x * TB;

  if (tid < TB) { slp_s[tid] = 0.0f; plp_s[tid] = 0.0f; ep_s[tid] = 1.0f; }

  // ---- stage attr tile, transposed to k-major (8 rows x 128 = one pass) ----
  {
    int r = tid >> 5;            // 0..7
    int cm = (tid & 31) << 2;    // 0,4,...,124
    F4 vv; vv.v = *(const float4*)&attr[(size_t)(b0 + r) * ADIM + cm];
    attr_s[cm + 0][r] = vv.f[0];
    attr_s[cm + 1][r] = vv.f[1];
    attr_s[cm + 2][r] = vv.f[2];
    attr_s[cm + 3][r] = vv.f[3];
  }
  __syncthreads();

  // ---- h0 = attr @ W_a^T + b_a : acc[phys sample] for this thread's unit ----
  {
    float acc[8];
    #pragma unroll
    for (int s = 0; s < 8; ++s) acc[s] = 0.0f;
    #pragma unroll 2
    for (int k = 0; k < ADIM; ++k) {
      F4 a0, a1;
      a0.v = *(const float4*)&attr_s[k][0];
      a1.v = *(const float4*)&attr_s[k][4];
      float wa = WaT[(k << 8) + u];
      #pragma unroll
      for (int j = 0; j < 4; ++j) {
        acc[j]     = fmaf(a0.f[j], wa, acc[j]);
        acc[4 + j] = fmaf(a1.f[j], wa, acc[4 + j]);
      }
    }
    float ba = b_a[u];
    #pragma unroll
    for (int s = 0; s < 8; ++s) h_s[u][s] = acc[s] + ba;
  }
  __syncthreads();

  // persistent per-thread state: cell state, slot s = phys sample (s+w2)&7
  float c_r[8];
  #pragma unroll
  for (int s = 0; s < 8; ++s) c_r[s] = 0.0f;

  float bg[4];  // b_ih + b_hh per gate for this unit
  #pragma unroll
  for (int g = 0; g < 4; ++g) bg[g] = b_ih[(g << 8) + u] + b_hh[(g << 8) + u];
  const float bv = b_v[lane];

  // ---- initial LSTM step, x = 0 ----
  {
    float ga[8][4];  // [slot][gate]
    #pragma unroll
    for (int s = 0; s < 8; ++s)
      #pragma unroll
      for (int g = 0; g < 4; ++g) ga[s][g] = 0.0f;
    #pragma unroll 1
    for (int kc = 0; kc < 16; ++kc) {
      const int k0 = kc << 4;
      const int kk = k0 + (lane & 15);
      float hch[8];
      #pragma unroll
      for (int s = 0; s < 8; ++s) hch[s] = h_s[kk][(s + w2) & 7];
      #pragma unroll
      for (int t = 0; t < 16; ++t) {
        const int k = k0 + t;
        F4 wv4; wv4.v = *(const float4*)&WhhT4[(k << 10) + (u << 2)];
        #pragma unroll
        for (int s = 0; s < 8; ++s) {
          float hb = bcast(hch[s], t);
          ga[s][0] = fmaf(hb, wv4.f[0], ga[s][0]);
          ga[s][1] = fmaf(hb, wv4.f[1], ga[s][1]);
          ga[s][2] = fmaf(hb, wv4.f[2], ga[s][2]);
          ga[s][3] = fmaf(hb, wv4.f[3], ga[s][3]);
        }
      }
    }
    __syncthreads();  // all reads of h_s done before overwrite
    float hn[8];
    #pragma unroll
    for (int s = 0; s < 8; ++s) {
      float gi = ga[s][0] + bg[0];
      float gf = ga[s][1] + bg[1];
      float gg = ga[s][2] + bg[2];
      float go = ga[s][3] + bg[3];
      float cn = sigm(gf) * c_r[s] + sigm(gi) * tanhf(gg);
      hn[s] = sigm(go) * tanhf(cn);
      c_r[s] = cn;
    }
    #pragma unroll
    for (int s = 0; s < 8; ++s) h_s[u][(s + w2) & 7] = hn[s];
    __syncthreads();
  }

  // ---- 20 sampled steps ----
  #pragma unroll 1
  for (int l = 0; l < NSTEP; ++l) {
    uint32_t kl0, kl1;
    threefry2x32(0u, 42u, 0u, (uint32_t)l, kl0, kl1);

    const bool last = (l == NSTEP - 1);
    float la[2] = {0.0f, 0.0f};  // logits for phys samples w2, w2+1; v=lane
    float ga[8][4];  // [slot][gate]
    #pragma unroll
    for (int s = 0; s < 8; ++s)
      #pragma unroll
      for (int g = 0; g < 4; ++g) ga[s][g] = 0.0f;

    if (!last) {
      #pragma unroll 1
      for (int kc = 0; kc < 16; ++kc) {
        const int k0 = kc << 4;
        const int kk = k0 + (lane & 15);
        float hch[8];
        #pragma unroll
        for (int s = 0; s < 8; ++s) hch[s] = h_s[kk][(s + w2) & 7];
        #pragma unroll
        for (int t = 0; t < 16; ++t) {
          const int k = k0 + t;
          F4 wv4; wv4.v = *(const float4*)&WhhT4[(k << 10) + (u << 2)];
          float wvv = WvT[(k << 6) | lane];
          #pragma unroll
          for (int s = 0; s < 8; ++s) {
            float hb = bcast(hch[s], t);
            if (s < 2) la[s] = fmaf(hb, wvv, la[s]);  // slots 0..1 = phys w2, w2+1
            ga[s][0] = fmaf(hb, wv4.f[0], ga[s][0]);
            ga[s][1] = fmaf(hb, wv4.f[1], ga[s][1]);
            ga[s][2] = fmaf(hb, wv4.f[2], ga[s][2]);
            ga[s][3] = fmaf(hb, wv4.f[3], ga[s][3]);
          }
        }
      }
    } else {
      // logits only
      #pragma unroll 1
      for (int kc = 0; kc < 16; ++kc) {
        const int k0 = kc << 4;
        const int kk = k0 + (lane & 15);
        float hch[2];
        #pragma unroll
        for (int s = 0; s < 2; ++s) hch[s] = h_s[kk][(s + w2) & 7];
        #pragma unroll
        for (int t = 0; t < 16; ++t) {
          const int k = k0 + t;
          float wvv = WvT[(k << 6) | lane];
          #pragma unroll
          for (int s = 0; s < 2; ++s) la[s] = fmaf(bcast(hch[s], t), wvv, la[s]);
        }
      }
    }

    // ---- sampling: wave w handles phys samples w2, w2+1; lane holds logit[b][lane] ----
    #pragma unroll
    for (int db = 0; db < 2; ++db) {
      float x = la[db] + bv;  // logits = h@W_v^T + b_v
      float m = x;
      #pragma unroll
      for (int o = 32; o > 0; o >>= 1) m = fmaxf(m, __shfl_xor(m, o));
      float e = expf(x - m);
      float s = e;
      #pragma unroll
      for (int o = 32; o > 0; o >>= 1) s += __shfl_xor(s, o);
      float lse = logf(s);
      float logp = x - m - lse;
      float p = expf(logp);
      float pe = p * logp;
      #pragma unroll
      for (int o = 32; o > 0; o >>= 1) pe += __shfl_xor(pe, o);
      uint32_t idx = ((uint32_t)(b0 + w2 + db) << 6) | (uint32_t)lane;
      uint32_t r0, r1;
      threefry2x32(kl0, kl1, 0u, idx, r0, r1);
      uint32_t bits = r0 ^ r1;
      float f01 = __uint_as_float((bits >> 9) | 0x3f800000u) - 1.0f;
      const float TINY = 1.17549435e-38f;
      float uu2 = fmaxf(TINY, f01 + TINY);
      float gn = -logf(-logf(uu2));
      float y = gn + x;
      float by = y; int bi = lane;
      #pragma unroll
      for (int o = 32; o > 0; o >>= 1) {
        float oy = __shfl_xor(by, o);
        int oi = __shfl_xor(bi, o);
        if (oy > by || (oy == by && oi < bi)) { by = oy; bi = oi; }
      }
      float lp = __shfl(logp, bi, 64);
      if (lane == 0) {
        int bb = w2 + db;
        ch_s[bb] = bi;
        slp_s[bb] += lp;
        plp_s[bb] += pe;
        ep_s[bb] *= expf(lp);
        out[(size_t)(b0 + bb) * NSTEP + l] = (float)bi;
      }
    }

    if (!last) {
      __syncthreads();  // everyone finished reading h_s; ch_s visible
      float hn[8];
      #pragma unroll
      for (int s = 0; s < 8; ++s) {
        const int sp = (s + w2) & 7;  // physical sample for this slot
        F4 wi; wi.v = *(const float4*)&WihT4[(ch_s[sp] << 10) + (u << 2)];
        float gi = ga[s][0] + wi.f[0] + bg[0];
        float gf = ga[s][1] + wi.f[1] + bg[1];
        float gg = ga[s][2] + wi.f[2] + bg[2];
        float go = ga[s][3] + wi.f[3] + bg[3];
        float cn = sigm(gf) * c_r[s] + sigm(gi) * tanhf(gg);
        hn[s] = sigm(go) * tanhf(cn);
        c_r[s] = cn;
      }
      #pragma unroll
      for (int s = 0; s < 8; ++s) h_s[u][(s + w2) & 7] = hn[s];
      __syncthreads();
    }
  }

  __syncthreads();
  if (tid < TB) {
    int bb = b0 + tid;
    out[(size_t)BATCH * NSTEP + bb]             = slp_s[tid];
    out[(size_t)BATCH * NSTEP + BATCH + bb]     = plp_s[tid];
    out[(size_t)BATCH * NSTEP + 2 * BATCH + bb] = ep_s[tid];
  }
}

extern "C" void kernel_launch(void* const* d_in, const int* in_sizes, int n_in,
                              void* d_out, int out_size, void* d_ws, size_t ws_size,
                              hipStream_t stream) {
  // setup_inputs order:
  // 0 attrVector [8192,128], 1 W_a [256,128], 2 b_a [256], 3 W_ih [1024,64],
  // 4 W_hh [1024,256], 5 b_ih [1024], 6 b_hh [1024], 7 W_v [64,256], 8 b_v [64]
  const float* attr = (const float*)d_in[0];
  const float* W_a  = (const float*)d_in[1];
  const float* b_a  = (const float*)d_in[2];
  const float* W_ih = (const float*)d_in[3];
  const float* W_hh = (const float*)d_in[4];
  const float* b_ih = (const float*)d_in[5];
  const float* b_hh = (const float*)d_in[6];
  const float* W_v  = (const float*)d_in[7];
  const float* b_v  = (const float*)d_in[8];
  float* ws = (float*)d_ws;

  prep_kernel<<<256, 256, 0, stream>>>(W_hh, W_v, W_a, W_ih, ws);
  sender_main<<<BATCH / TB, 256, 0, stream>>>(
      attr, b_a, b_ih, b_hh, b_v,
      ws, ws + 262144, ws + 278528, ws + 311296,
      (float*)d_out);
}

// Round 7
// 1517.630 us; speedup vs baseline: 1.0896x; 1.0045x over previous
//
#include <hip/hip_runtime.h>
#include <stdint.h>

#define BATCH 8192
#define ADIM 128
#define HDIM 256
#define VDIM 64
#define NSTEP 20
#define TB 8     // samples per block: 1024 blocks -> 4 blocks/CU -> 4 waves/SIMD
#define HSP 9    // h_s stride (floats): ODD -> lane-distributed b32 reads are conflict-free
#define ASP 12   // attr_s stride: 48B rows, 16B-aligned for b128 staging reads

typedef union { float4 v; float f[4]; } F4;

// ---------------- Threefry-2x32 (exactly JAX's lowering) ----------------
__device__ __forceinline__ uint32_t rotl32(uint32_t x, uint32_t d) {
  return (x << d) | (x >> (32u - d));
}
__device__ __forceinline__ void tf4(uint32_t& x0, uint32_t& x1, int r0, int r1, int r2, int r3) {
  x0 += x1; x1 = rotl32(x1, r0); x1 ^= x0;
  x0 += x1; x1 = rotl32(x1, r1); x1 ^= x0;
  x0 += x1; x1 = rotl32(x1, r2); x1 ^= x0;
  x0 += x1; x1 = rotl32(x1, r3); x1 ^= x0;
}
__device__ __forceinline__ void threefry2x32(uint32_t k0, uint32_t k1, uint32_t x0, uint32_t x1,
                                             uint32_t& o0, uint32_t& o1) {
  uint32_t k2 = k0 ^ k1 ^ 0x1BD11BDAu;
  x0 += k0; x1 += k1;
  tf4(x0, x1, 13, 15, 26, 6);  x0 += k1; x1 += k2 + 1u;
  tf4(x0, x1, 17, 29, 16, 24); x0 += k2; x1 += k0 + 2u;
  tf4(x0, x1, 13, 15, 26, 6);  x0 += k0; x1 += k1 + 3u;
  tf4(x0, x1, 17, 29, 16, 24); x0 += k1; x1 += k2 + 4u;
  tf4(x0, x1, 13, 15, 26, 6);  x0 += k2; x1 += k0 + 5u;
  o0 = x0; o1 = x1;
}

__device__ __forceinline__ float sigm(float x) { return 1.0f / (1.0f + expf(-x)); }

// wave-uniform broadcast of lane t's value -> SGPR (feeds v_fma scalar slot)
__device__ __forceinline__ float bcast(float x, int t) {
  return __int_as_float(__builtin_amdgcn_readlane(__float_as_int(x), t));
}

// ---------------- prep: repack weights, gate-interleaved per unit ----------------
// ws layout (floats): WhhT4[256][256][4] @0      (k, unit, gate)  1 MB
//                     WvT  [256][64]     @262144 (k, v)
//                     WaT  [128][256]    @278528 (k, unit)
//                     WihT4[64][256][4]  @311296 (v, unit, gate)
__global__ void prep_kernel(const float* __restrict__ Whh, const float* __restrict__ Wv,
                            const float* __restrict__ Wa, const float* __restrict__ Wih,
                            float* __restrict__ ws) {
  int n = blockIdx.x * blockDim.x + threadIdx.x;
  int stride = gridDim.x * blockDim.x;
  float* WhhT4 = ws;
  float* WvT   = ws + 262144;
  float* WaT   = ws + 278528;
  float* WihT4 = ws + 311296;
  for (int i = n; i < 256 * 1024; i += stride) {
    int k = i >> 10, rem = i & 1023, u = rem >> 2, g = rem & 3;
    WhhT4[i] = Whh[((g << 8) + u) * 256 + k];
  }
  for (int i = n; i < 256 * 64; i += stride) { int k = i >> 6, v = i & 63; WvT[i] = Wv[v * 256 + k]; }
  for (int i = n; i < 128 * 256; i += stride) { int k = i >> 8, uu = i & 255; WaT[i] = Wa[uu * 128 + k]; }
  for (int i = n; i < 64 * 1024; i += stride) {
    int v = i >> 10, rem = i & 1023, uu = rem >> 2, g = rem & 3;
    WihT4[i] = Wih[((g << 8) + uu) * 64 + v];
  }
}

// ---------------- main persistent kernel ----------------
// 1024 blocks x 256 threads; block owns TB=8 samples for all 21 steps.
// R7 vs R6: ONLY __launch_bounds__ 4 -> 2. R6's (256,4) made the allocator
// target 64 VGPRs (8-waves/SIMD headroom the 1024-block grid can't use) and
// spill ~10 regs/thread: FETCH 8.4->225 MB, WRITE 0.74->197 MB of scratch
// round-trips. Under (256,2) the compiler allocates what it needs (~80);
// anything <=128 VGPR still physically admits 4 waves/SIMD, and occupancy
// stays grid-limited at 4 blocks/CU. All per-sample arithmetic and
// per-accumulator k-ascending order identical to R1 -> bit-exact.
// Lane = unit (u = 64w+lane); thread computes 4 gates x 8 samples for its unit.
// Per-wave sample rotation: slot s holds PHYSICAL sample (s+2w)&7, so the
// wave's logit samples are always slots 0..1 (compile-time register indices).
__global__ __launch_bounds__(256, 2) void sender_main(
    const float* __restrict__ attr, const float* __restrict__ b_a,
    const float* __restrict__ b_ih, const float* __restrict__ b_hh,
    const float* __restrict__ b_v,
    const float* __restrict__ WhhT4, const float* __restrict__ WvT,
    const float* __restrict__ WaT, const float* __restrict__ WihT4,
    float* __restrict__ out) {
  __shared__ float h_s[HDIM][HSP];                    // h_s[k][phys sample]
  __shared__ __align__(16) float attr_s[ADIM][ASP];   // attr_s[k][sample]
  __shared__ float slp_s[TB], plp_s[TB], ep_s[TB];
  __shared__ int ch_s[TB];

  const int tid = threadIdx.x;
  const int w = tid >> 6;         // wave id
  const int lane = tid & 63;
  const int u = (w << 6) + lane;  // unit owned by this thread
  const int w2 = w << 1;          // first (physical) sample this wave samples
  const int b0 = blockIdx.x * TB;

  if (tid < TB) { slp_s[tid] = 0.0f; plp_s[tid] = 0.0f; ep_s[tid] = 1.0f; }

  // ---- stage attr tile, transposed to k-major (8 rows x 128 = one pass) ----
  {
    int r = tid >> 5;            // 0..7
    int cm = (tid & 31) << 2;    // 0,4,...,124
    F4 vv; vv.v = *(const float4*)&attr[(size_t)(b0 + r) * ADIM + cm];
    attr_s[cm + 0][r] = vv.f[0];
    attr_s[cm + 1][r] = vv.f[1];
    attr_s[cm + 2][r] = vv.f[2];
    attr_s[cm + 3][r] = vv.f[3];
  }
  __syncthreads();

  // ---- h0 = attr @ W_a^T + b_a : acc[phys sample] for this thread's unit ----
  {
    float acc[8];
    #pragma unroll
    for (int s = 0; s < 8; ++s) acc[s] = 0.0f;
    #pragma unroll 2
    for (int k = 0; k < ADIM; ++k) {
      F4 a0, a1;
      a0.v = *(const float4*)&attr_s[k][0];
      a1.v = *(const float4*)&attr_s[k][4];
      float wa = WaT[(k << 8) + u];
      #pragma unroll
      for (int j = 0; j < 4; ++j) {
        acc[j]     = fmaf(a0.f[j], wa, acc[j]);
        acc[4 + j] = fmaf(a1.f[j], wa, acc[4 + j]);
      }
    }
    float ba = b_a[u];
    #pragma unroll
    for (int s = 0; s < 8; ++s) h_s[u][s] = acc[s] + ba;
  }
  __syncthreads();

  // persistent per-thread state: cell state, slot s = phys sample (s+w2)&7
  float c_r[8];
  #pragma unroll
  for (int s = 0; s < 8; ++s) c_r[s] = 0.0f;

  float bg[4];  // b_ih + b_hh per gate for this unit
  #pragma unroll
  for (int g = 0; g < 4; ++g) bg[g] = b_ih[(g << 8) + u] + b_hh[(g << 8) + u];
  const float bv = b_v[lane];

  // ---- initial LSTM step, x = 0 ----
  {
    float ga[8][4];  // [slot][gate]
    #pragma unroll
    for (int s = 0; s < 8; ++s)
      #pragma unroll
      for (int g = 0; g < 4; ++g) ga[s][g] = 0.0f;
    #pragma unroll 1
    for (int kc = 0; kc < 16; ++kc) {
      const int k0 = kc << 4;
      const int kk = k0 + (lane & 15);
      float hch[8];
      #pragma unroll
      for (int s = 0; s < 8; ++s) hch[s] = h_s[kk][(s + w2) & 7];
      #pragma unroll
      for (int t = 0; t < 16; ++t) {
        const int k = k0 + t;
        F4 wv4; wv4.v = *(const float4*)&WhhT4[(k << 10) + (u << 2)];
        #pragma unroll
        for (int s = 0; s < 8; ++s) {
          float hb = bcast(hch[s], t);
          ga[s][0] = fmaf(hb, wv4.f[0], ga[s][0]);
          ga[s][1] = fmaf(hb, wv4.f[1], ga[s][1]);
          ga[s][2] = fmaf(hb, wv4.f[2], ga[s][2]);
          ga[s][3] = fmaf(hb, wv4.f[3], ga[s][3]);
        }
      }
    }
    __syncthreads();  // all reads of h_s done before overwrite
    float hn[8];
    #pragma unroll
    for (int s = 0; s < 8; ++s) {
      float gi = ga[s][0] + bg[0];
      float gf = ga[s][1] + bg[1];
      float gg = ga[s][2] + bg[2];
      float go = ga[s][3] + bg[3];
      float cn = sigm(gf) * c_r[s] + sigm(gi) * tanhf(gg);
      hn[s] = sigm(go) * tanhf(cn);
      c_r[s] = cn;
    }
    #pragma unroll
    for (int s = 0; s < 8; ++s) h_s[u][(s + w2) & 7] = hn[s];
    __syncthreads();
  }

  // ---- 20 sampled steps ----
  #pragma unroll 1
  for (int l = 0; l < NSTEP; ++l) {
    uint32_t kl0, kl1;
    threefry2x32(0u, 42u, 0u, (uint32_t)l, kl0, kl1);

    const bool last = (l == NSTEP - 1);
    float la[2] = {0.0f, 0.0f};  // logits for phys samples w2, w2+1; v=lane
    float ga[8][4];  // [slot][gate]
    #pragma unroll
    for (int s = 0; s < 8; ++s)
      #pragma unroll
      for (int g = 0; g < 4; ++g) ga[s][g] = 0.0f;

    if (!last) {
      #pragma unroll 1
      for (int kc = 0; kc < 16; ++kc) {
        const int k0 = kc << 4;
        const int kk = k0 + (lane & 15);
        float hch[8];
        #pragma unroll
        for (int s = 0; s < 8; ++s) hch[s] = h_s[kk][(s + w2) & 7];
        #pragma unroll
        for (int t = 0; t < 16; ++t) {
          const int k = k0 + t;
          F4 wv4; wv4.v = *(const float4*)&WhhT4[(k << 10) + (u << 2)];
          float wvv = WvT[(k << 6) | lane];
          #pragma unroll
          for (int s = 0; s < 8; ++s) {
            float hb = bcast(hch[s], t);
            if (s < 2) la[s] = fmaf(hb, wvv, la[s]);  // slots 0..1 = phys w2, w2+1
            ga[s][0] = fmaf(hb, wv4.f[0], ga[s][0]);
            ga[s][1] = fmaf(hb, wv4.f[1], ga[s][1]);
            ga[s][2] = fmaf(hb, wv4.f[2], ga[s][2]);
            ga[s][3] = fmaf(hb, wv4.f[3], ga[s][3]);
          }
        }
      }
    } else {
      // logits only
      #pragma unroll 1
      for (int kc = 0; kc < 16; ++kc) {
        const int k0 = kc << 4;
        const int kk = k0 + (lane & 15);
        float hch[2];
        #pragma unroll
        for (int s = 0; s < 2; ++s) hch[s] = h_s[kk][(s + w2) & 7];
        #pragma unroll
        for (int t = 0; t < 16; ++t) {
          const int k = k0 + t;
          float wvv = WvT[(k << 6) | lane];
          #pragma unroll
          for (int s = 0; s < 2; ++s) la[s] = fmaf(bcast(hch[s], t), wvv, la[s]);
        }
      }
    }

    // ---- sampling: wave w handles phys samples w2, w2+1; lane holds logit[b][lane] ----
    #pragma unroll
    for (int db = 0; db < 2; ++db) {
      float x = la[db] + bv;  // logits = h@W_v^T + b_v
      float m = x;
      #pragma unroll
      for (int o = 32; o > 0; o >>= 1) m = fmaxf(m, __shfl_xor(m, o));
      float e = expf(x - m);
      float s = e;
      #pragma unroll
      for (int o = 32; o > 0; o >>= 1) s += __shfl_xor(s, o);
      float lse = logf(s);
      float logp = x - m - lse;
      float p = expf(logp);
      float pe = p * logp;
      #pragma unroll
      for (int o = 32; o > 0; o >>= 1) pe += __shfl_xor(pe, o);
      uint32_t idx = ((uint32_t)(b0 + w2 + db) << 6) | (uint32_t)lane;
      uint32_t r0, r1;
      threefry2x32(kl0, kl1, 0u, idx, r0, r1);
      uint32_t bits = r0 ^ r1;
      float f01 = __uint_as_float((bits >> 9) | 0x3f800000u) - 1.0f;
      const float TINY = 1.17549435e-38f;
      float uu2 = fmaxf(TINY, f01 + TINY);
      float gn = -logf(-logf(uu2));
      float y = gn + x;
      float by = y; int bi = lane;
      #pragma unroll
      for (int o = 32; o > 0; o >>= 1) {
        float oy = __shfl_xor(by, o);
        int oi = __shfl_xor(bi, o);
        if (oy > by || (oy == by && oi < bi)) { by = oy; bi = oi; }
      }
      float lp = __shfl(logp, bi, 64);
      if (lane == 0) {
        int bb = w2 + db;
        ch_s[bb] = bi;
        slp_s[bb] += lp;
        plp_s[bb] += pe;
        ep_s[bb] *= expf(lp);
        out[(size_t)(b0 + bb) * NSTEP + l] = (float)bi;
      }
    }

    if (!last) {
      __syncthreads();  // everyone finished reading h_s; ch_s visible
      float hn[8];
      #pragma unroll
      for (int s = 0; s < 8; ++s) {
        const int sp = (s + w2) & 7;  // physical sample for this slot
        F4 wi; wi.v = *(const float4*)&WihT4[(ch_s[sp] << 10) + (u << 2)];
        float gi = ga[s][0] + wi.f[0] + bg[0];
        float gf = ga[s][1] + wi.f[1] + bg[1];
        float gg = ga[s][2] + wi.f[2] + bg[2];
        float go = ga[s][3] + wi.f[3] + bg[3];
        float cn = sigm(gf) * c_r[s] + sigm(gi) * tanhf(gg);
        hn[s] = sigm(go) * tanhf(cn);
        c_r[s] = cn;
      }
      #pragma unroll
      for (int s = 0; s < 8; ++s) h_s[u][(s + w2) & 7] = hn[s];
      __syncthreads();
    }
  }

  __syncthreads();
  if (tid < TB) {
    int bb = b0 + tid;
    out[(size_t)BATCH * NSTEP + bb]             = slp_s[tid];
    out[(size_t)BATCH * NSTEP + BATCH + bb]     = plp_s[tid];
    out[(size_t)BATCH * NSTEP + 2 * BATCH + bb] = ep_s[tid];
  }
}

extern "C" void kernel_launch(void* const* d_in, const int* in_sizes, int n_in,
                              void* d_out, int out_size, void* d_ws, size_t ws_size,
                              hipStream_t stream) {
  // setup_inputs order:
  // 0 attrVector [8192,128], 1 W_a [256,128], 2 b_a [256], 3 W_ih [1024,64],
  // 4 W_hh [1024,256], 5 b_ih [1024], 6 b_hh [1024], 7 W_v [64,256], 8 b_v [64]
  const float* attr = (const float*)d_in[0];
  const float* W_a  = (const float*)d_in[1];
  const float* b_a  = (const float*)d_in[2];
  const float* W_ih = (const float*)d_in[3];
  const float* W_hh = (const float*)d_in[4];
  const float* b_ih = (const float*)d_in[5];
  const float* b_hh = (const float*)d_in[6];
  const float* W_v  = (const float*)d_in[7];
  const float* b_v  = (const float*)d_in[8];
  float* ws = (float*)d_ws;

  prep_kernel<<<256, 256, 0, stream>>>(W_hh, W_v, W_a, W_ih, ws);
  sender_main<<<BATCH / TB, 256, 0, stream>>>(
      attr, b_a, b_ih, b_hh, b_v,
      ws, ws + 262144, ws + 278528, ws + 311296,
      (float*)d_out);
}